// Round 8
// baseline (34769.653 us; speedup 1.0000x reference)
//
#include <hip/hip_runtime.h>
#include <hip/hip_bf16.h>

#define T_SEQ  1024
#define DMODEL 513
#define DINNER 1026
#define DSTATE 16
#define DCONV  4
#define DTRANK 33
#define NLAYER 4
#define XZ_LD  (2*DINNER)            // 2052
#define DBL_LD (DTRANK + 2*DSTATE)   // 65
#define TC     256                   // time chunk
#define NC     (T_SEQ/TC)            // 4

#define GM_PLAIN 0
#define GM_SOFTPLUS 1
#define GM_RESID 2

// C[r,n] = sum_k A[r,k]*B[n,k]; rows r < negrows write 0 (pre-sequence history rows).
__global__ __launch_bounds__(256) void gemm_naive_k(
    const float* __restrict__ A, int lda,
    const float* __restrict__ B, int ldb,
    float* __restrict__ C, int ldc,
    int M, int N, int K, int negrows,
    const float* __restrict__ bias,
    const float* __restrict__ resid,   // same ld/row-base as C
    int mode)
{
    int col = blockIdx.x * 16 + (threadIdx.x & 15);
    int row = blockIdx.y * 16 + (threadIdx.x >> 4);
    if (row >= M || col >= N) return;
    float acc = 0.f;
    if (row >= negrows) {
        const float* a = A + (ptrdiff_t)row * lda;
        const float* b = B + (size_t)col * ldb;
        for (int k = 0; k < K; ++k) acc = fmaf(a[k], b[k], acc);
        if (mode == GM_SOFTPLUS) {
            acc += bias[col];
            acc = (acc > 20.f) ? acc : log1pf(expf(acc));   // softplus
        } else if (mode == GM_RESID) {
            acc += resid[(size_t)row * ldc + col];
        }
    }
    C[(size_t)row * ldc + col] = acc;
}

// chunk conv: xzc rows r=0..258 map to global time t0-3+r; output local rows 0..255
__global__ __launch_bounds__(256) void conv_silu_k(
    const float* __restrict__ xzc,   // (TC+3, 2052)
    const float* __restrict__ cw,    // (DINNER, 4)
    const float* __restrict__ cb,    // (DINNER)
    float* __restrict__ xac,         // (TC, DINNER)
    int t0)
{
    int idx = blockIdx.x * 256 + threadIdx.x;
    if (idx >= TC * DINNER) return;
    int l = idx / DINNER;
    int c = idx - l * DINNER;
    float accv = cb[c];
#pragma unroll
    for (int k = 0; k < DCONV; ++k) {
        int gtt = t0 + l + k - (DCONV - 1);        // global time of this tap
        if (gtt >= 0)
            accv = fmaf(xzc[(size_t)(l + k) * XZ_LD + c], cw[c*DCONV + k], accv);
    }
    xac[idx] = accv / (1.f + expf(-accv));          // SiLU
}

// chunk scan: one thread per channel, 16 states in registers, h carried via ws.
// dty holds dt on entry, y on exit (in-place; each slot read before written).
__global__ __launch_bounds__(64) void scan_k(
    float* __restrict__ dty,         // (TC, DINNER)
    const float* __restrict__ xac,   // (TC, DINNER)
    const float* __restrict__ dblc,  // (TC, 65): B at 33+n, C at 49+n
    const float* __restrict__ xzc,   // (TC+3, 2052): z at row l+3, col DINNER+c
    const float* __restrict__ A_log, // (DINNER, 16)
    const float* __restrict__ Dp,    // (DINNER)
    float* __restrict__ hws,         // (DINNER, 16) persistent state
    int first)
{
    int c = blockIdx.x * 64 + threadIdx.x;
    if (c >= DINNER) return;
    float Ac[DSTATE], h[DSTATE];
#pragma unroll
    for (int n = 0; n < DSTATE; ++n) {
        Ac[n] = -expf(A_log[(size_t)c*DSTATE + n]);
        h[n] = first ? 0.f : hws[(size_t)c*DSTATE + n];
    }
    float dc = Dp[c];
    for (int l = 0; l < TC; ++l) {
        float dtv = dty[(size_t)l*DINNER + c];
        float xav = xac[(size_t)l*DINNER + c];
        float dx  = dtv * xav;
        float acc = 0.f;
#pragma unroll
        for (int n = 0; n < DSTATE; ++n) {
            float Bv = dblc[(size_t)l*DBL_LD + DTRANK + n];
            float Cv = dblc[(size_t)l*DBL_LD + DTRANK + DSTATE + n];
            h[n] = h[n] * expf(dtv * Ac[n]) + dx * Bv;   // h = dA*h + dBx
            acc  = fmaf(h[n], Cv, acc);                  // y_t = h @ C_t
        }
        float zv = xzc[(size_t)(l + 3) * XZ_LD + DINNER + c];
        dty[(size_t)l*DINNER + c] = (acc + dc * xav) * (zv / (1.f + expf(-zv)));
    }
#pragma unroll
    for (int n = 0; n < DSTATE; ++n) hws[(size_t)c*DSTATE + n] = h[n];
}

// per-row LayerNorm over DMODEL=513, in place
__global__ __launch_bounds__(256) void layernorm_k(
    float* __restrict__ x, const float* __restrict__ g, const float* __restrict__ b)
{
    __shared__ float red[256];
    int t = blockIdx.x;
    float* row = x + (size_t)t * DMODEL;
    float s = 0.f;
    for (int j = threadIdx.x; j < DMODEL; j += 256) s += row[j];
    red[threadIdx.x] = s; __syncthreads();
    for (int st = 128; st > 0; st >>= 1) {
        if (threadIdx.x < st) red[threadIdx.x] += red[threadIdx.x + st];
        __syncthreads();
    }
    float mu = red[0] / (float)DMODEL;
    __syncthreads();
    float sq = 0.f;
    for (int j = threadIdx.x; j < DMODEL; j += 256) { float d = row[j] - mu; sq += d*d; }
    red[threadIdx.x] = sq; __syncthreads();
    for (int st = 128; st > 0; st >>= 1) {
        if (threadIdx.x < st) red[threadIdx.x] += red[threadIdx.x + st];
        __syncthreads();
    }
    float inv = rsqrtf(red[0] / (float)DMODEL + 1e-5f);
    for (int j = threadIdx.x; j < DMODEL; j += 256)
        row[j] = (row[j] - mu) * inv * g[j] + b[j];
}

__global__ void transpose_k(const float* __restrict__ Z, float* __restrict__ x)
{
    int idx = blockIdx.x * 256 + threadIdx.x;
    if (idx < T_SEQ * DMODEL) {
        int t = idx / DMODEL;
        int d = idx - t * DMODEL;
        x[idx] = Z[(size_t)d * T_SEQ + t];
    }
}

// FP32 output write (the round-1..7 bug: out is float32, NOT bf16)
__global__ void extract_k(const float* __restrict__ x, float* __restrict__ out, int i)
{
    if (threadIdx.x == 0 && blockIdx.x == 0)
        out[i] = x[(size_t)(T_SEQ-1)*DMODEL + (DMODEL-1)];
}

__global__ void zero_out_k(float* __restrict__ out)
{
    if (threadIdx.x < 4 && blockIdx.x == 0) out[threadIdx.x] = 0.f;
}

// find the `occ`-th input with exactly `want` elements (identity under dict order)
static const float* by_size(void* const* d_in, const int* in_sizes, int n_in,
                            int want, int occ)
{
    int seen = 0;
    for (int j = 0; j < n_in; ++j)
        if (in_sizes[j] == want) { if (seen == occ) return (const float*)d_in[j]; ++seen; }
    return nullptr;
}

extern "C" void kernel_launch(void* const* d_in, const int* in_sizes, int n_in,
                              void* d_out, int out_size, void* d_ws, size_t ws_size,
                              hipStream_t stream)
{
    float* out = (float*)d_out;      // FP32 output

    const float* Z      = by_size(d_in, in_sizes, n_in, 525312, 0);
    const float* in_w   = by_size(d_in, in_sizes, n_in, 4210704, 0);
    const float* conv_w = by_size(d_in, in_sizes, n_in, 16416, 0);
    const float* conv_b = by_size(d_in, in_sizes, n_in, 4104, 0);
    const float* xp_w   = by_size(d_in, in_sizes, n_in, 266760, 0);
    const float* dtp_w  = by_size(d_in, in_sizes, n_in, 135432, 0);
    const float* dtp_b  = by_size(d_in, in_sizes, n_in, 4104, 1);
    const float* A_log  = by_size(d_in, in_sizes, n_in, 65664, 0);
    const float* Dp     = by_size(d_in, in_sizes, n_in, 4104, 2);
    const float* out_w  = by_size(d_in, in_sizes, n_in, 2105352, 0);
    const float* norm_g = by_size(d_in, in_sizes, n_in, 2052, 0);
    const float* norm_b = by_size(d_in, in_sizes, n_in, 2052, 1);

    // compact chunked workspace: ~8.56 MB
    float* w = (float*)d_ws;
    w += 64;
    float* xbuf  = w;  w += (size_t)T_SEQ * DMODEL;      // 525312
    float* x2buf = w;  w += (size_t)T_SEQ * DMODEL;      // 525312
    float* xzc   = w;  w += (size_t)(TC + 3) * XZ_LD;    // 531468
    float* xac   = w;  w += (size_t)TC * DINNER;         // 262656
    float* dblc  = w;  w += (size_t)TC * DBL_LD;         // 16640
    float* dtc   = w;  w += (size_t)TC * DINNER;         // 262656 (dt, then y in-place)
    float* hws   = w;  w += (size_t)DINNER * DSTATE;     // 16416
    size_t need_bytes = (size_t)(w - (float*)d_ws) * sizeof(float);

    if (!Z || !in_w || !conv_w || !conv_b || !xp_w || !dtp_w || !dtp_b ||
        !A_log || !Dp || !out_w || !norm_g || !norm_b || ws_size < need_bytes) {
        zero_out_k<<<dim3(1), 64, 0, stream>>>(out);
        return;
    }

    transpose_k<<<dim3((T_SEQ*DMODEL + 255)/256), 256, 0, stream>>>(Z, xbuf);

    for (int i = 0; i < NLAYER; ++i) {
        const float* inw = in_w  + (size_t)i * (2*DINNER) * DMODEL;
        const float* cw  = conv_w + (size_t)i * DINNER * DCONV;
        const float* cb  = conv_b + (size_t)i * DINNER;
        const float* xpw = xp_w  + (size_t)i * DBL_LD * DINNER;
        const float* dtw = dtp_w + (size_t)i * DINNER * DTRANK;
        const float* dtb = dtp_b + (size_t)i * DINNER;
        const float* Al  = A_log + (size_t)i * DINNER * DSTATE;
        const float* Dpp = Dp    + (size_t)i * DINNER;
        const float* ow  = out_w + (size_t)i * DMODEL * DINNER;

        for (int half = 0; half < 2; ++half) {
            const float* xin   = (half == 0) ? xbuf  : x2buf;
            float*       xout  = (half == 0) ? x2buf : xbuf;
            const float* resid = (half == 0) ? xbuf  : nullptr;

            for (int ci = 0; ci < NC; ++ci) {
                int t0 = ci * TC;
                // 1. xzc[r] = (x @ in_w^T)[t0-3+r]  (259 rows; rows with t<0 zeroed)
                gemm_naive_k<<<dim3((2*DINNER+15)/16, (TC+3+15)/16), 256, 0, stream>>>(
                    xin + (ptrdiff_t)(t0 - 3) * DMODEL, DMODEL, inw, DMODEL,
                    xzc, XZ_LD, TC + 3, 2*DINNER, DMODEL, (t0 == 0) ? 3 : 0,
                    nullptr, nullptr, GM_PLAIN);
                // 2. conv + silu -> xac
                conv_silu_k<<<dim3((TC*DINNER + 255)/256), 256, 0, stream>>>(
                    xzc, cw, cb, xac, t0);
                // 3. dblc = xac @ xp_w^T  (256 x 65, K=1026)
                gemm_naive_k<<<dim3((DBL_LD+15)/16, (TC+15)/16), 256, 0, stream>>>(
                    xac, DINNER, xpw, DINNER, dblc, DBL_LD,
                    TC, DBL_LD, DINNER, 0, nullptr, nullptr, GM_PLAIN);
                // 4. dtc = softplus(dblc[:, :33] @ dtp_w^T + dtp_b)
                gemm_naive_k<<<dim3((DINNER+15)/16, (TC+15)/16), 256, 0, stream>>>(
                    dblc, DBL_LD, dtw, DTRANK, dtc, DINNER,
                    TC, DINNER, DTRANK, 0, dtb, nullptr, GM_SOFTPLUS);
                // 5. scan chunk (dt -> y in place; h carried in hws)
                scan_k<<<dim3((DINNER+63)/64), 64, 0, stream>>>(
                    dtc, xac, dblc, xzc, Al, Dpp, hws, (ci == 0) ? 1 : 0);
                // 6. xout[t0..t0+255] = y @ out_w^T (+resid)
                gemm_naive_k<<<dim3((DMODEL+15)/16, (TC+15)/16), 256, 0, stream>>>(
                    dtc, DINNER, ow, DINNER, xout + (size_t)t0 * DMODEL, DMODEL,
                    TC, DMODEL, DINNER, 0, nullptr,
                    resid ? resid + (size_t)t0 * DMODEL : nullptr,
                    resid ? GM_RESID : GM_PLAIN);
            }
        }
        layernorm_k<<<dim3(T_SEQ), 256, 0, stream>>>(
            xbuf, norm_g + (size_t)i*DMODEL, norm_b + (size_t)i*DMODEL);
        extract_k<<<dim3(1), 64, 0, stream>>>(xbuf, out, i);
    }
}

// Round 9
// 10463.492 us; speedup vs baseline: 3.3229x; 3.3229x over previous
//
#include <hip/hip_runtime.h>
#include <hip/hip_bf16.h>

#define T_SEQ  1024
#define DMODEL 513
#define DINNER 1026
#define DSTATE 16
#define DCONV  4
#define DTRANK 33
#define NLAYER 4
#define XZ_LD  (2*DINNER)            // 2052
#define DBL_LD (DTRANK + 2*DSTATE)   // 65

#define GM_PLAIN 0
#define GM_SOFTPLUS 1
#define GM_RESID 2

// Tiled GEMM: C[m,n] = sum_k A[m,k]*B[n,k]  (B row-major (N,K) => C = A @ B^T)
// 64x64 tile, 256 threads, 4x4 microtile, LDS-staged with +1-pad stride 65.
__global__ __launch_bounds__(256) void gemm_tiled_k(
    const float* __restrict__ A, int lda,
    const float* __restrict__ B, int ldb,
    float* __restrict__ C, int ldc,
    int M, int N, int K,
    const float* __restrict__ bias,
    const float* __restrict__ resid,   // same ld/row-base as C
    int mode)
{
    __shared__ float As[16][65];
    __shared__ float Bs[16][65];
    int tid = threadIdx.x;
    int tx = tid & 15, ty = tid >> 4;
    int m0 = blockIdx.y * 64, n0 = blockIdx.x * 64;
    float acc[4][4] = {};

    for (int k0 = 0; k0 < K; k0 += 16) {
        int k = k0 + tx;
        bool kin = (k < K);
#pragma unroll
        for (int s = 0; s < 4; ++s) {
            int m = m0 + ty + 16*s;
            As[tx][ty + 16*s] = (kin && m < M) ? A[(size_t)m*lda + k] : 0.f;
            int n = n0 + ty + 16*s;
            Bs[tx][ty + 16*s] = (kin && n < N) ? B[(size_t)n*ldb + k] : 0.f;
        }
        __syncthreads();
#pragma unroll
        for (int kk = 0; kk < 16; ++kk) {
            float a[4], b[4];
#pragma unroll
            for (int i = 0; i < 4; ++i) a[i] = As[kk][ty + 16*i];
#pragma unroll
            for (int j = 0; j < 4; ++j) b[j] = Bs[kk][tx + 16*j];
#pragma unroll
            for (int i = 0; i < 4; ++i)
#pragma unroll
                for (int j = 0; j < 4; ++j)
                    acc[i][j] = fmaf(a[i], b[j], acc[i][j]);
        }
        __syncthreads();
    }

#pragma unroll
    for (int i = 0; i < 4; ++i) {
        int row = m0 + ty + 16*i;
        if (row >= M) continue;
#pragma unroll
        for (int j = 0; j < 4; ++j) {
            int col = n0 + tx + 16*j;
            if (col >= N) continue;
            float v = acc[i][j];
            if (mode == GM_SOFTPLUS) {
                v += bias[col];
                v = (v > 20.f) ? v : log1pf(__expf(v));     // softplus
            } else if (mode == GM_RESID) {
                v += resid[(size_t)row*ldc + col];
            }
            C[(size_t)row*ldc + col] = v;
        }
    }
}

// causal depthwise conv (kernel 4) + SiLU.  xi = xz[:, :DINNER] (row stride XZ_LD)
__global__ __launch_bounds__(256) void conv_silu_k(
    const float* __restrict__ xz,
    const float* __restrict__ cw,   // (DINNER, 4)
    const float* __restrict__ cb,   // (DINNER)
    float* __restrict__ xa)         // (T, DINNER)
{
    int idx = blockIdx.x * 256 + threadIdx.x;
    if (idx >= T_SEQ * DINNER) return;
    int t = idx / DINNER;
    int c = idx - t * DINNER;
    float accv = cb[c];
#pragma unroll
    for (int k = 0; k < DCONV; ++k) {
        int tt = t + k - (DCONV - 1);
        if (tt >= 0) accv = fmaf(xz[(size_t)tt*XZ_LD + c], cw[c*DCONV + k], accv);
    }
    xa[idx] = accv / (1.f + __expf(-accv));   // SiLU
}

// SSM scan: 16 lanes per channel (one per state), shuffle-reduce over states.
// Fuses y = (ys + D*xa) * silu(z).
__global__ __launch_bounds__(256) void scan_shfl_k(
    const float* __restrict__ dt,    // (T, DINNER)
    const float* __restrict__ xa,    // (T, DINNER)
    const float* __restrict__ dbl,   // (T, 65): B at 33+n, C at 49+n
    const float* __restrict__ A_log, // (DINNER, 16)
    const float* __restrict__ Dp,    // (DINNER)
    const float* __restrict__ xz,    // (T, 2052): z at col DINNER+c
    float* __restrict__ y)           // (T, DINNER)
{
    int tid = threadIdx.x;
    int n  = tid & 15;
    int cl = tid >> 4;                  // 0..15
    int c  = blockIdx.x * 16 + cl;
    bool valid = (c < DINNER);
    int cc = valid ? c : DINNER - 1;    // clamp; invalid lanes discard
    float Ac = -__expf(A_log[(size_t)cc*DSTATE + n]);
    float dc = Dp[cc];
    float h = 0.f;
    for (int t = 0; t < T_SEQ; ++t) {
        float dtv = dt[(size_t)t*DINNER + cc];
        float xav = xa[(size_t)t*DINNER + cc];
        float Bv = dbl[(size_t)t*DBL_LD + DTRANK + n];
        float Cv = dbl[(size_t)t*DBL_LD + DTRANK + DSTATE + n];
        float dA = __expf(dtv * Ac);
        h = fmaf(h, dA, dtv * xav * Bv);
        float p = h * Cv;
        p += __shfl_xor(p, 1);
        p += __shfl_xor(p, 2);
        p += __shfl_xor(p, 4);
        p += __shfl_xor(p, 8);
        if (n == 0 && valid) {
            float zv = xz[(size_t)t*XZ_LD + DINNER + c];
            y[(size_t)t*DINNER + c] = (p + dc * xav) * (zv / (1.f + __expf(-zv)));
        }
    }
}

// per-row LayerNorm over DMODEL=513, in place
__global__ __launch_bounds__(256) void layernorm_k(
    float* __restrict__ x, const float* __restrict__ g, const float* __restrict__ b)
{
    __shared__ float red[256];
    int t = blockIdx.x;
    float* row = x + (size_t)t * DMODEL;
    float s = 0.f;
    for (int j = threadIdx.x; j < DMODEL; j += 256) s += row[j];
    red[threadIdx.x] = s; __syncthreads();
    for (int st = 128; st > 0; st >>= 1) {
        if (threadIdx.x < st) red[threadIdx.x] += red[threadIdx.x + st];
        __syncthreads();
    }
    float mu = red[0] / (float)DMODEL;
    __syncthreads();
    float sq = 0.f;
    for (int j = threadIdx.x; j < DMODEL; j += 256) { float d = row[j] - mu; sq += d*d; }
    red[threadIdx.x] = sq; __syncthreads();
    for (int st = 128; st > 0; st >>= 1) {
        if (threadIdx.x < st) red[threadIdx.x] += red[threadIdx.x + st];
        __syncthreads();
    }
    float inv = rsqrtf(red[0] / (float)DMODEL + 1e-5f);
    for (int j = threadIdx.x; j < DMODEL; j += 256)
        row[j] = (row[j] - mu) * inv * g[j] + b[j];
}

__global__ void transpose_k(const float* __restrict__ Z, float* __restrict__ x)
{
    int idx = blockIdx.x * 256 + threadIdx.x;
    if (idx < T_SEQ * DMODEL) {
        int t = idx / DMODEL;
        int d = idx - t * DMODEL;
        x[idx] = Z[(size_t)d * T_SEQ + t];
    }
}

// FP32 output (the round-1..7 lesson: d_out is float32)
__global__ void extract_k(const float* __restrict__ x, float* __restrict__ out, int i)
{
    if (threadIdx.x == 0 && blockIdx.x == 0)
        out[i] = x[(size_t)(T_SEQ-1)*DMODEL + (DMODEL-1)];
}

__global__ void zero_out_k(float* __restrict__ out)
{
    if (threadIdx.x < 4 && blockIdx.x == 0) out[threadIdx.x] = 0.f;
}

static const float* by_size(void* const* d_in, const int* in_sizes, int n_in,
                            int want, int occ)
{
    int seen = 0;
    for (int j = 0; j < n_in; ++j)
        if (in_sizes[j] == want) { if (seen == occ) return (const float*)d_in[j]; ++seen; }
    return nullptr;
}

extern "C" void kernel_launch(void* const* d_in, const int* in_sizes, int n_in,
                              void* d_out, int out_size, void* d_ws, size_t ws_size,
                              hipStream_t stream)
{
    float* out = (float*)d_out;      // FP32 output

    const float* Z      = by_size(d_in, in_sizes, n_in, 525312, 0);
    const float* in_w   = by_size(d_in, in_sizes, n_in, 4210704, 0);
    const float* conv_w = by_size(d_in, in_sizes, n_in, 16416, 0);
    const float* conv_b = by_size(d_in, in_sizes, n_in, 4104, 0);
    const float* xp_w   = by_size(d_in, in_sizes, n_in, 266760, 0);
    const float* dtp_w  = by_size(d_in, in_sizes, n_in, 135432, 0);
    const float* dtp_b  = by_size(d_in, in_sizes, n_in, 4104, 1);
    const float* A_log  = by_size(d_in, in_sizes, n_in, 65664, 0);
    const float* Dp     = by_size(d_in, in_sizes, n_in, 4104, 2);
    const float* out_w  = by_size(d_in, in_sizes, n_in, 2105352, 0);
    const float* norm_g = by_size(d_in, in_sizes, n_in, 2052, 0);
    const float* norm_b = by_size(d_in, in_sizes, n_in, 2052, 1);

    // full-T workspace: 6,828,610 floats ≈ 24.3 MB (rounds 1-3 proved ws_size >= this)
    float* w = (float*)d_ws;
    w += 64;
    float* xbuf  = w;  w += (size_t)T_SEQ * DMODEL;      // 525312
    float* x2buf = w;  w += (size_t)T_SEQ * DMODEL;      // 525312
    float* xzbuf = w;  w += (size_t)T_SEQ * XZ_LD;       // 2101248
    float* xabuf = w;  w += (size_t)T_SEQ * DINNER;      // 1050624
    float* dblbuf= w;  w += (size_t)T_SEQ * DBL_LD;      // 66560
    float* dtbuf = w;  w += (size_t)T_SEQ * DINNER;      // 1050624
    float* ybuf  = w;  w += (size_t)T_SEQ * DINNER;      // 1050624
    size_t need_bytes = (size_t)(w - (float*)d_ws) * sizeof(float);

    if (!Z || !in_w || !conv_w || !conv_b || !xp_w || !dtp_w || !dtp_b ||
        !A_log || !Dp || !out_w || !norm_g || !norm_b || ws_size < need_bytes) {
        zero_out_k<<<dim3(1), 64, 0, stream>>>(out);
        return;
    }

    transpose_k<<<dim3((T_SEQ*DMODEL + 255)/256), 256, 0, stream>>>(Z, xbuf);

    for (int i = 0; i < NLAYER; ++i) {
        const float* inw = in_w  + (size_t)i * (2*DINNER) * DMODEL;
        const float* cw  = conv_w + (size_t)i * DINNER * DCONV;
        const float* cb  = conv_b + (size_t)i * DINNER;
        const float* xpw = xp_w  + (size_t)i * DBL_LD * DINNER;
        const float* dtw = dtp_w + (size_t)i * DINNER * DTRANK;
        const float* dtb = dtp_b + (size_t)i * DINNER;
        const float* Al  = A_log + (size_t)i * DINNER * DSTATE;
        const float* Dpp = Dp    + (size_t)i * DINNER;
        const float* ow  = out_w + (size_t)i * DMODEL * DINNER;

        for (int half = 0; half < 2; ++half) {
            const float* xin   = (half == 0) ? xbuf  : x2buf;
            float*       xout  = (half == 0) ? x2buf : xbuf;
            const float* resid = (half == 0) ? xbuf  : nullptr;

            // 1. xz = x @ in_w^T   (1024 x 2052, K=513)
            gemm_tiled_k<<<dim3((2*DINNER+63)/64, T_SEQ/64), 256, 0, stream>>>(
                xin, DMODEL, inw, DMODEL, xzbuf, XZ_LD,
                T_SEQ, 2*DINNER, DMODEL, nullptr, nullptr, GM_PLAIN);
            // 2. conv + silu -> xa
            conv_silu_k<<<dim3((T_SEQ*DINNER + 255)/256), 256, 0, stream>>>(
                xzbuf, cw, cb, xabuf);
            // 3. dbl = xa @ xp_w^T  (1024 x 65, K=1026)
            gemm_tiled_k<<<dim3((DBL_LD+63)/64, T_SEQ/64), 256, 0, stream>>>(
                xabuf, DINNER, xpw, DINNER, dblbuf, DBL_LD,
                T_SEQ, DBL_LD, DINNER, nullptr, nullptr, GM_PLAIN);
            // 4. dt = softplus(dbl[:, :33] @ dtp_w^T + dtp_b)  (1024 x 1026, K=33)
            gemm_tiled_k<<<dim3((DINNER+63)/64, T_SEQ/64), 256, 0, stream>>>(
                dblbuf, DBL_LD, dtw, DTRANK, dtbuf, DINNER,
                T_SEQ, DINNER, DTRANK, dtb, nullptr, GM_SOFTPLUS);
            // 5. scan -> y (fused D*xa + silu(z) gate)
            scan_shfl_k<<<dim3((DINNER+15)/16), 256, 0, stream>>>(
                dtbuf, xabuf, dblbuf, Al, Dpp, xzbuf, ybuf);
            // 6. xout = y @ out_w^T (+resid)  (1024 x 513, K=1026)
            gemm_tiled_k<<<dim3((DMODEL+63)/64, T_SEQ/64), 256, 0, stream>>>(
                ybuf, DINNER, ow, DINNER, xout, DMODEL,
                T_SEQ, DMODEL, DINNER, nullptr, resid,
                resid ? GM_RESID : GM_PLAIN);
        }
        layernorm_k<<<dim3(T_SEQ), 256, 0, stream>>>(
            xbuf, norm_g + (size_t)i*DMODEL, norm_b + (size_t)i*DMODEL);
        extract_k<<<dim3(1), 64, 0, stream>>>(xbuf, out, i);
    }
}

// Round 11
// 4833.805 us; speedup vs baseline: 7.1930x; 2.1646x over previous
//
#include <hip/hip_runtime.h>
#include <hip/hip_bf16.h>

#define T_SEQ  1024
#define DMODEL 513
#define DINNER 1026
#define DSTATE 16
#define DCONV  4
#define DTRANK 33
#define NLAYER 4
#define XZ_LD  (2*DINNER)            // 2052
#define DBL_LD (DTRANK + 2*DSTATE)   // 65
#define NCHUNK 32
#define CLEN   (T_SEQ/NCHUNK)        // 32

#define GM_PLAIN 0
#define GM_SOFTPLUS 1
#define GM_RESID 2

// Tiled GEMM: C[m,n] = sum_k A[m,k]*B[n,k]  (B row-major (N,K) => C = A @ B^T)
__global__ __launch_bounds__(256) void gemm_tiled_k(
    const float* __restrict__ A, int lda,
    const float* __restrict__ B, int ldb,
    float* __restrict__ C, int ldc,
    int M, int N, int K,
    const float* __restrict__ bias,
    const float* __restrict__ resid,
    int mode)
{
    __shared__ float As[16][65];
    __shared__ float Bs[16][65];
    int tid = threadIdx.x;
    int tx = tid & 15, ty = tid >> 4;
    int m0 = blockIdx.y * 64, n0 = blockIdx.x * 64;
    float acc[4][4] = {};

    for (int k0 = 0; k0 < K; k0 += 16) {
        int k = k0 + tx;
        bool kin = (k < K);
#pragma unroll
        for (int s = 0; s < 4; ++s) {
            int m = m0 + ty + 16*s;
            As[tx][ty + 16*s] = (kin && m < M) ? A[(size_t)m*lda + k] : 0.f;
            int n = n0 + ty + 16*s;
            Bs[tx][ty + 16*s] = (kin && n < N) ? B[(size_t)n*ldb + k] : 0.f;
        }
        __syncthreads();
#pragma unroll
        for (int kk = 0; kk < 16; ++kk) {
            float a[4], b[4];
#pragma unroll
            for (int i = 0; i < 4; ++i) a[i] = As[kk][ty + 16*i];
#pragma unroll
            for (int j = 0; j < 4; ++j) b[j] = Bs[kk][tx + 16*j];
#pragma unroll
            for (int i = 0; i < 4; ++i)
#pragma unroll
                for (int j = 0; j < 4; ++j)
                    acc[i][j] = fmaf(a[i], b[j], acc[i][j]);
        }
        __syncthreads();
    }

#pragma unroll
    for (int i = 0; i < 4; ++i) {
        int row = m0 + ty + 16*i;
        if (row >= M) continue;
#pragma unroll
        for (int j = 0; j < 4; ++j) {
            int col = n0 + tx + 16*j;
            if (col >= N) continue;
            float v = acc[i][j];
            if (mode == GM_SOFTPLUS) {
                v += bias[col];
                v = (v > 20.f) ? v : log1pf(__expf(v));
            } else if (mode == GM_RESID) {
                v += resid[(size_t)row*ldc + col];
            }
            C[(size_t)row*ldc + col] = v;
        }
    }
}

// causal depthwise conv (kernel 4) + SiLU
__global__ __launch_bounds__(256) void conv_silu_k(
    const float* __restrict__ xz,
    const float* __restrict__ cw, const float* __restrict__ cb,
    float* __restrict__ xa)
{
    int idx = blockIdx.x * 256 + threadIdx.x;
    if (idx >= T_SEQ * DINNER) return;
    int t = idx / DINNER;
    int c = idx - t * DINNER;
    float accv = cb[c];
#pragma unroll
    for (int k = 0; k < DCONV; ++k) {
        int tt = t + k - (DCONV - 1);
        if (tt >= 0) accv = fmaf(xz[(size_t)tt*XZ_LD + c], cw[c*DCONV + k], accv);
    }
    xa[idx] = accv / (1.f + __expf(-accv));
}

// Chunked scan pass 1: per (channel, chunk) compute local scan from h=0.
// Outputs: hloc[k][c][n] (end state) and aprod[k][c][n] (prod of dA).
__global__ __launch_bounds__(256) void scan_part1_k(
    const float* __restrict__ dt,    // (T, DINNER)
    const float* __restrict__ xa,    // (T, DINNER)
    const float* __restrict__ dbl,   // (T, 65): B at 33+n
    const float* __restrict__ A_log, // (DINNER, 16)
    float* __restrict__ aprod,       // (NCHUNK, DINNER, 16)
    float* __restrict__ hloc)        // (NCHUNK, DINNER, 16)
{
    int idx = blockIdx.x * 256 + threadIdx.x;
    int c = idx % DINNER;
    int k = idx / DINNER;
    if (k >= NCHUNK) return;
    float Ac[DSTATE], h[DSTATE], P[DSTATE];
#pragma unroll
    for (int n = 0; n < DSTATE; ++n) {
        Ac[n] = -__expf(A_log[(size_t)c*DSTATE + n]);
        h[n] = 0.f; P[n] = 1.f;
    }
    int t0 = k * CLEN;
    for (int l = 0; l < CLEN; ++l) {
        int t = t0 + l;
        float dtv = dt[(size_t)t*DINNER + c];
        float xav = xa[(size_t)t*DINNER + c];
        float dx  = dtv * xav;
        const float* Bp = dbl + (size_t)t*DBL_LD + DTRANK;
#pragma unroll
        for (int n = 0; n < DSTATE; ++n) {
            float e = __expf(dtv * Ac[n]);
            h[n] = fmaf(h[n], e, dx * Bp[n]);
            P[n] *= e;
        }
    }
    size_t o = ((size_t)k * DINNER + c) * DSTATE;
#pragma unroll
    for (int q = 0; q < 4; ++q) {
        *(float4*)(aprod + o + 4*q) = make_float4(P[4*q], P[4*q+1], P[4*q+2], P[4*q+3]);
        *(float4*)(hloc  + o + 4*q) = make_float4(h[4*q], h[4*q+1], h[4*q+2], h[4*q+3]);
    }
}

// Pass 2: sequential combine over chunks; writes h_in for each chunk in-place
// over aprod.  h_in(k) = carry;  carry = hloc(k) + aprod(k)*carry.
__global__ __launch_bounds__(256) void scan_combine_k(
    float* __restrict__ aprod_hin,   // in: aprod, out: h_in
    const float* __restrict__ hloc)
{
    int idx = blockIdx.x * 256 + threadIdx.x;   // (c,n) pair
    if (idx >= DINNER * DSTATE) return;
    float carry = 0.f;
    for (int k = 0; k < NCHUNK; ++k) {
        size_t o = (size_t)k * DINNER * DSTATE + idx;
        float P  = aprod_hin[o];
        float hl = hloc[o];
        aprod_hin[o] = carry;
        carry = fmaf(P, carry, hl);
    }
}

// Pass 3: re-run local scan seeded with h_in; emit gated y IN-PLACE over dt.
__global__ __launch_bounds__(256) void scan_part3_k(
    float* __restrict__ dty,         // (T, DINNER): dt in, y out
    const float* __restrict__ xa,
    const float* __restrict__ dbl,   // B at 33+n, C at 49+n
    const float* __restrict__ xz,    // z at col DINNER+c
    const float* __restrict__ A_log,
    const float* __restrict__ Dp,
    const float* __restrict__ hin)   // (NCHUNK, DINNER, 16)
{
    int idx = blockIdx.x * 256 + threadIdx.x;
    int c = idx % DINNER;
    int k = idx / DINNER;
    if (k >= NCHUNK) return;
    float Ac[DSTATE], h[DSTATE];
    size_t o = ((size_t)k * DINNER + c) * DSTATE;
#pragma unroll
    for (int q = 0; q < 4; ++q) {
        float4 v = *(const float4*)(hin + o + 4*q);
        h[4*q] = v.x; h[4*q+1] = v.y; h[4*q+2] = v.z; h[4*q+3] = v.w;
    }
#pragma unroll
    for (int n = 0; n < DSTATE; ++n)
        Ac[n] = -__expf(A_log[(size_t)c*DSTATE + n]);
    float dc = Dp[c];
    int t0 = k * CLEN;
    for (int l = 0; l < CLEN; ++l) {
        int t = t0 + l;
        float dtv = dty[(size_t)t*DINNER + c];
        float xav = xa[(size_t)t*DINNER + c];
        float dx  = dtv * xav;
        const float* Bp = dbl + (size_t)t*DBL_LD + DTRANK;
        const float* Cp = Bp + DSTATE;
        float acc = 0.f;
#pragma unroll
        for (int n = 0; n < DSTATE; ++n) {
            float e = __expf(dtv * Ac[n]);
            h[n] = fmaf(h[n], e, dx * Bp[n]);
            acc  = fmaf(h[n], Cp[n], acc);
        }
        float zv = xz[(size_t)t*XZ_LD + DINNER + c];
        dty[(size_t)t*DINNER + c] = (acc + dc * xav) * (zv / (1.f + __expf(-zv)));
    }
}

// per-row LayerNorm over DMODEL=513, in place
__global__ __launch_bounds__(256) void layernorm_k(
    float* __restrict__ x, const float* __restrict__ g, const float* __restrict__ b)
{
    __shared__ float red[256];
    int t = blockIdx.x;
    float* row = x + (size_t)t * DMODEL;
    float s = 0.f;
    for (int j = threadIdx.x; j < DMODEL; j += 256) s += row[j];
    red[threadIdx.x] = s; __syncthreads();
    for (int st = 128; st > 0; st >>= 1) {
        if (threadIdx.x < st) red[threadIdx.x] += red[threadIdx.x + st];
        __syncthreads();
    }
    float mu = red[0] / (float)DMODEL;
    __syncthreads();
    float sq = 0.f;
    for (int j = threadIdx.x; j < DMODEL; j += 256) { float d = row[j] - mu; sq += d*d; }
    red[threadIdx.x] = sq; __syncthreads();
    for (int st = 128; st > 0; st >>= 1) {
        if (threadIdx.x < st) red[threadIdx.x] += red[threadIdx.x + st];
        __syncthreads();
    }
    float inv = rsqrtf(red[0] / (float)DMODEL + 1e-5f);
    for (int j = threadIdx.x; j < DMODEL; j += 256)
        row[j] = (row[j] - mu) * inv * g[j] + b[j];
}

__global__ void transpose_k(const float* __restrict__ Z, float* __restrict__ x)
{
    int idx = blockIdx.x * 256 + threadIdx.x;
    if (idx < T_SEQ * DMODEL) {
        int t = idx / DMODEL;
        int d = idx - t * DMODEL;
        x[idx] = Z[(size_t)d * T_SEQ + t];
    }
}

__global__ void extract_k(const float* __restrict__ x, float* __restrict__ out, int i)
{
    if (threadIdx.x == 0 && blockIdx.x == 0)
        out[i] = x[(size_t)(T_SEQ-1)*DMODEL + (DMODEL-1)];
}

__global__ void zero_out_k(float* __restrict__ out)
{
    if (threadIdx.x < 4 && blockIdx.x == 0) out[threadIdx.x] = 0.f;
}

static const float* by_size(void* const* d_in, const int* in_sizes, int n_in,
                            int want, int occ)
{
    int seen = 0;
    for (int j = 0; j < n_in; ++j)
        if (in_sizes[j] == want) { if (seen == occ) return (const float*)d_in[j]; ++seen; }
    return nullptr;
}

extern "C" void kernel_launch(void* const* d_in, const int* in_sizes, int n_in,
                              void* d_out, int out_size, void* d_ws, size_t ws_size,
                              hipStream_t stream)
{
    float* out = (float*)d_out;      // FP32 output

    const float* Z      = by_size(d_in, in_sizes, n_in, 525312, 0);
    const float* in_w   = by_size(d_in, in_sizes, n_in, 4210704, 0);
    const float* conv_w = by_size(d_in, in_sizes, n_in, 16416, 0);
    const float* conv_b = by_size(d_in, in_sizes, n_in, 4104, 0);
    const float* xp_w   = by_size(d_in, in_sizes, n_in, 266760, 0);
    const float* dtp_w  = by_size(d_in, in_sizes, n_in, 135432, 0);
    const float* dtp_b  = by_size(d_in, in_sizes, n_in, 4104, 1);
    const float* A_log  = by_size(d_in, in_sizes, n_in, 65664, 0);
    const float* Dp     = by_size(d_in, in_sizes, n_in, 4104, 2);
    const float* out_w  = by_size(d_in, in_sizes, n_in, 2105352, 0);
    const float* norm_g = by_size(d_in, in_sizes, n_in, 2052, 0);
    const float* norm_b = by_size(d_in, in_sizes, n_in, 2052, 1);

    // workspace: 6,370,368 floats = 25.48 MB (same byte count as rounds 1-3/9 — proven fit)
    float* w = (float*)d_ws;
    w += 64;
    float* xbuf  = w;  w += (size_t)T_SEQ * DMODEL;          // 525312
    float* x2buf = w;  w += (size_t)T_SEQ * DMODEL;          // 525312
    float* xzbuf = w;  w += (size_t)T_SEQ * XZ_LD;           // 2101248
    float* xabuf = w;  w += (size_t)T_SEQ * DINNER;          // 1050624
    float* dblbuf= w;  w += (size_t)T_SEQ * DBL_LD;          // 66560
    float* dtbuf = w;  w += (size_t)T_SEQ * DINNER;          // 1050624 (dt -> y in-place)
    float* aprod = w;  w += (size_t)NCHUNK * DINNER * DSTATE;// 525312 (aprod -> h_in)
    float* hloc  = w;  w += (size_t)NCHUNK * DINNER * DSTATE;// 525312
    size_t need_bytes = (size_t)(w - (float*)d_ws) * sizeof(float);

    if (!Z || !in_w || !conv_w || !conv_b || !xp_w || !dtp_w || !dtp_b ||
        !A_log || !Dp || !out_w || !norm_g || !norm_b || ws_size < need_bytes) {
        zero_out_k<<<dim3(1), 64, 0, stream>>>(out);
        return;
    }

    const int scan_grid = (DINNER * NCHUNK + 255) / 256;   // 129

    transpose_k<<<dim3((T_SEQ*DMODEL + 255)/256), 256, 0, stream>>>(Z, xbuf);

    for (int i = 0; i < NLAYER; ++i) {
        const float* inw = in_w  + (size_t)i * (2*DINNER) * DMODEL;
        const float* cw  = conv_w + (size_t)i * DINNER * DCONV;
        const float* cb  = conv_b + (size_t)i * DINNER;
        const float* xpw = xp_w  + (size_t)i * DBL_LD * DINNER;
        const float* dtw = dtp_w + (size_t)i * DINNER * DTRANK;
        const float* dtb = dtp_b + (size_t)i * DINNER;
        const float* Al  = A_log + (size_t)i * DINNER * DSTATE;
        const float* Dpp = Dp    + (size_t)i * DINNER;
        const float* ow  = out_w + (size_t)i * DMODEL * DINNER;

        for (int half = 0; half < 2; ++half) {
            const float* xin   = (half == 0) ? xbuf  : x2buf;
            float*       xout  = (half == 0) ? x2buf : xbuf;
            const float* resid = (half == 0) ? xbuf  : nullptr;

            // 1. xz = x @ in_w^T   (1024 x 2052, K=513)
            gemm_tiled_k<<<dim3((2*DINNER+63)/64, T_SEQ/64), 256, 0, stream>>>(
                xin, DMODEL, inw, DMODEL, xzbuf, XZ_LD,
                T_SEQ, 2*DINNER, DMODEL, nullptr, nullptr, GM_PLAIN);
            // 2. conv + silu -> xa
            conv_silu_k<<<dim3((T_SEQ*DINNER + 255)/256), 256, 0, stream>>>(
                xzbuf, cw, cb, xabuf);
            // 3. dbl = xa @ xp_w^T  (1024 x 65, K=1026)
            gemm_tiled_k<<<dim3((DBL_LD+63)/64, T_SEQ/64), 256, 0, stream>>>(
                xabuf, DINNER, xpw, DINNER, dblbuf, DBL_LD,
                T_SEQ, DBL_LD, DINNER, nullptr, nullptr, GM_PLAIN);
            // 4. dt = softplus(dbl[:, :33] @ dtp_w^T + dtp_b)  (1024 x 1026, K=33)
            gemm_tiled_k<<<dim3((DINNER+63)/64, T_SEQ/64), 256, 0, stream>>>(
                dblbuf, DBL_LD, dtw, DTRANK, dtbuf, DINNER,
                T_SEQ, DINNER, DTRANK, dtb, nullptr, GM_SOFTPLUS);
            // 5. chunked scan: dt -> y in place
            scan_part1_k<<<dim3(scan_grid), 256, 0, stream>>>(
                dtbuf, xabuf, dblbuf, Al, aprod, hloc);
            scan_combine_k<<<dim3((DINNER*DSTATE + 255)/256), 256, 0, stream>>>(
                aprod, hloc);
            scan_part3_k<<<dim3(scan_grid), 256, 0, stream>>>(
                dtbuf, xabuf, dblbuf, xzbuf, Al, Dpp, aprod);
            // 6. xout = y @ out_w^T (+resid)  (1024 x 513, K=1026)
            gemm_tiled_k<<<dim3((DMODEL+63)/64, T_SEQ/64), 256, 0, stream>>>(
                dtbuf, DINNER, ow, DINNER, xout, DMODEL,
                T_SEQ, DMODEL, DINNER, nullptr, resid,
                resid ? GM_RESID : GM_PLAIN);
        }
        layernorm_k<<<dim3(T_SEQ), 256, 0, stream>>>(
            xbuf, norm_g + (size_t)i*DMODEL, norm_b + (size_t)i*DMODEL);
        extract_k<<<dim3(1), 64, 0, stream>>>(xbuf, out, i);
    }
}